// Round 3
// baseline (2420.224 us; speedup 1.0000x reference)
//
#include <hip/hip_runtime.h>
#include <stdint.h>
#include <string.h>

// Problem dims (fixed by the reference)
#define BDIM   4096
#define INDIM  1024
#define XDIM   2048
#define OUTDIM 512

#define LO_SCALE 2048.0f         // 2^11: lifts fp16 lo-plane out of subnormals
#define INV_LO_SCALE (1.0f / 2048.0f)

typedef _Float16 f16x8 __attribute__((ext_vector_type(8)));
typedef float f32x4 __attribute__((ext_vector_type(4)));

__device__ __forceinline__ unsigned short h2u(_Float16 h) {
  unsigned short u;
  memcpy(&u, &h, 2);
  return u;
}

// split f32 into hi fp16 + scaled-lo fp16 (combined ~22 mantissa bits)
__device__ __forceinline__ void split_h(float v, unsigned short& h,
                                        unsigned short& l) {
  _Float16 hh = (_Float16)v;                       // RTNE
  float r = v - (float)hh;                         // exact (Sterbenz-ish, fits)
  _Float16 ll = (_Float16)(r * LO_SCALE);          // |r|*2^11 <= |v|, no inf
  h = h2u(hh);
  l = h2u(ll);
}

// async global->LDS, 16B per lane; LDS dest wave-uniform base + lane*16
__device__ __forceinline__ void gld_lds16(const void* g, void* l) {
  __builtin_amdgcn_global_load_lds(
      (const __attribute__((address_space(1))) uint32_t*)g,
      (__attribute__((address_space(3))) uint32_t*)l, 16, 0, 0);
}

// fused RandomActivation + clip (relu/sigmoid/tanh/leaky(.1)/selu), libm-grade
__device__ __forceinline__ float rand_act(float v, int a, float mo) {
  float r;
  if (a == 0) {
    r = fmaxf(v, 0.0f);
  } else if (a == 1) {
    r = 1.0f / (1.0f + expf(-v));
  } else if (a == 2) {
    r = tanhf(v);
  } else if (a == 3) {
    r = (v >= 0.0f) ? v : 0.1f * v;
  } else {  // selu (matches jax: scale * where(v>0, v, alpha*expm1(v)))
    r = (v > 0.0f) ? 1.0507009873554805f * v
                   : 1.7580993408473766f * expm1f(v);
  }
  return fminf(r, mo);
}

// x (f32) -> hi/scaled-lo fp16 planes, 4 elems/thread
__global__ void cvt_split(const float* __restrict__ s,
                          unsigned short* __restrict__ dh,
                          unsigned short* __restrict__ dl, int n) {
  int i = (blockIdx.x * blockDim.x + threadIdx.x) * 4;
  if (i >= n) return;
  float4 v = *(const float4*)(s + i);
  ushort4 h, l;
  split_h(v.x, h.x, l.x);
  split_h(v.y, h.y, l.y);
  split_h(v.z, h.z, l.z);
  split_h(v.w, h.w, l.w);
  *(ushort4*)(dh + i) = h;
  *(ushort4*)(dl + i) = l;
}

// W (K x N, f32, row-major) -> WT hi/scaled-lo fp16 (N x K, row-major)
__global__ void transpose_cvt_split(const float* __restrict__ W,
                                    unsigned short* __restrict__ WTh,
                                    unsigned short* __restrict__ WTl, int K,
                                    int N) {
  __shared__ float t[32][33];
  int n0 = blockIdx.x * 32, k0 = blockIdx.y * 32;
  int tx = threadIdx.x, ty = threadIdx.y;  // 32 x 8
#pragma unroll
  for (int i = 0; i < 32; i += 8)
    t[ty + i][tx] = W[(size_t)(k0 + ty + i) * N + n0 + tx];
  __syncthreads();
#pragma unroll
  for (int i = 0; i < 32; i += 8) {
    float v = t[tx][ty + i];
    unsigned short h, l;
    split_h(v, h, l);
    size_t idx = (size_t)(n0 + ty + i) * K + k0 + tx;
    WTh[idx] = h;
    WTl[idx] = l;
  }
}

// C[M,N] = act( A[M,K] @ BT[N,K]^T + bias ), split-fp16 (3-term) precision.
// acc_hh holds hi*hi; acc_x holds hi*lo' + lo'*hi at scale 2^11 (no fp16
// subnormals possible in lo-planes). Final = acc_hh + acc_x/2^11.
// A split at Ksplit across (A1h/A1l, A2h/A2l) for the residual concat.
// 256 threads, 4 waves 2x2; block tile 128x128, BK=32, mfma 16x16x32 f16.
template <bool OUT_F16>
__global__ __launch_bounds__(256) void gemm_split_act(
    const short* __restrict__ A1h, const short* __restrict__ A1l,
    const short* __restrict__ A2h, const short* __restrict__ A2l,
    const short* __restrict__ BTh, const short* __restrict__ BTl,
    const float* __restrict__ bias, const float* __restrict__ mo,
    const int* __restrict__ aid, unsigned short* __restrict__ Ch,
    unsigned short* __restrict__ Cl, float* __restrict__ Cf, int N, int K,
    int Ksplit) {
  __shared__ short lAh[128 * 32];
  __shared__ short lAl[128 * 32];
  __shared__ short lBh[128 * 32];
  __shared__ short lBl[128 * 32];

  const int tid = threadIdx.x;
  const int lane = tid & 63;
  const int wave = tid >> 6;
  const int wm = wave >> 1, wn = wave & 1;
  const int m16 = lane & 15, quad = lane >> 4;

  const int blockN = blockIdx.x * 128;
  const int blockM = blockIdx.y * 128;

  f32x4 acc1[4][4];  // hi*hi
  f32x4 acc2[4][4];  // (hi*lo' + lo'*hi), scale 2^11
#pragma unroll
  for (int i = 0; i < 4; i++)
#pragma unroll
    for (int j = 0; j < 4; j++) {
      acc1[i][j] = (f32x4){0.f, 0.f, 0.f, 0.f};
      acc2[i][j] = (f32x4){0.f, 0.f, 0.f, 0.f};
    }

  const int lrow = lane >> 2;       // row within 16-row chunk
  const int lcol = (lane & 3) * 8;  // f16 col offset 0/8/16/24

  for (int k0 = 0; k0 < K; k0 += 32) {
    const short *Akh, *Akl;
    int koff, lda;
    if (k0 < Ksplit) {
      Akh = A1h; Akl = A1l; koff = k0; lda = Ksplit;
    } else {
      Akh = A2h; Akl = A2l; koff = k0 - Ksplit; lda = K - Ksplit;
    }

    __syncthreads();  // previous iter's ds_reads done before overwrite
#pragma unroll
    for (int t = 0; t < 2; t++) {
      int c = wave * 2 + t;  // chunk 0..7 (16 rows each)
      int r = c * 16 + lrow;
      size_t aoff = (size_t)(blockM + r) * lda + koff + lcol;
      size_t boff = (size_t)(blockN + r) * K + k0 + lcol;
      gld_lds16(Akh + aoff, &lAh[c * 512]);
      gld_lds16(Akl + aoff, &lAl[c * 512]);
      gld_lds16(BTh + boff, &lBh[c * 512]);
      gld_lds16(BTl + boff, &lBl[c * 512]);
    }
    __syncthreads();  // drains vmcnt: tiles visible

    // phase 1: hi x hi -> acc1
    f16x8 aH[4], bH[4];
#pragma unroll
    for (int t = 0; t < 4; t++) {
      aH[t] = *(const f16x8*)&lAh[(wm * 64 + t * 16 + m16) * 32 + quad * 8];
      bH[t] = *(const f16x8*)&lBh[(wn * 64 + t * 16 + m16) * 32 + quad * 8];
    }
#pragma unroll
    for (int i = 0; i < 4; i++)
#pragma unroll
      for (int j = 0; j < 4; j++)
        acc1[i][j] = __builtin_amdgcn_mfma_f32_16x16x32_f16(aH[i], bH[j],
                                                            acc1[i][j], 0, 0, 0);
    // phase 2: hi x lo' -> acc2
    {
      f16x8 bL[4];
#pragma unroll
      for (int t = 0; t < 4; t++)
        bL[t] = *(const f16x8*)&lBl[(wn * 64 + t * 16 + m16) * 32 + quad * 8];
#pragma unroll
      for (int i = 0; i < 4; i++)
#pragma unroll
        for (int j = 0; j < 4; j++)
          acc2[i][j] = __builtin_amdgcn_mfma_f32_16x16x32_f16(
              aH[i], bL[j], acc2[i][j], 0, 0, 0);
    }
    // phase 3: lo' x hi -> acc2
    {
      f16x8 aL[4];
#pragma unroll
      for (int t = 0; t < 4; t++)
        aL[t] = *(const f16x8*)&lAl[(wm * 64 + t * 16 + m16) * 32 + quad * 8];
#pragma unroll
      for (int i = 0; i < 4; i++)
#pragma unroll
        for (int j = 0; j < 4; j++)
          acc2[i][j] = __builtin_amdgcn_mfma_f32_16x16x32_f16(
              aL[i], bH[j], acc2[i][j], 0, 0, 0);
    }
  }

  // epilogue: combine accs, bias + per-column activation + clip
  // C/D map col=lane&15, row=quad*4+reg (m89-verified)
#pragma unroll
  for (int j = 0; j < 4; j++) {
    int col = blockN + wn * 64 + j * 16 + m16;
    float b = bias[col];
    float m = mo[col];
    int a = aid[col];
#pragma unroll
    for (int i = 0; i < 4; i++) {
#pragma unroll
      for (int r = 0; r < 4; r++) {
        int row = blockM + wm * 64 + i * 16 + quad * 4 + r;
        float s = acc1[i][j][r] + acc2[i][j][r] * INV_LO_SCALE;
        float v = rand_act(s + b, a, m);
        size_t idx = (size_t)row * N + col;
        if (OUT_F16) {
          unsigned short h, l;
          split_h(v, h, l);
          Ch[idx] = h;
          Cl[idx] = l;
        } else {
          Cf[idx] = v;
        }
      }
    }
  }
}

extern "C" void kernel_launch(void* const* d_in, const int* in_sizes, int n_in,
                              void* d_out, int out_size, void* d_ws,
                              size_t ws_size, hipStream_t stream) {
  (void)in_sizes; (void)n_in; (void)out_size; (void)ws_size;

  const float* x     = (const float*)d_in[0];
  const float* W_in  = (const float*)d_in[1];
  const float* b_in  = (const float*)d_in[2];
  const float* Wh[6] = {(const float*)d_in[3], (const float*)d_in[4],
                        (const float*)d_in[5], (const float*)d_in[6],
                        (const float*)d_in[7], (const float*)d_in[8]};
  const float* bh    = (const float*)d_in[9];
  const float* W_out = (const float*)d_in[10];
  const float* b_out = (const float*)d_in[11];
  const float* mo_in = (const float*)d_in[12];
  const float* mo_h  = (const float*)d_in[13];
  const float* mo_out= (const float*)d_in[14];
  const int* aid_in  = (const int*)d_in[15];
  const int* aid_h   = (const int*)d_in[16];
  const int* aid_out = (const int*)d_in[17];

  const int hin[6] = {XDIM, XDIM, 2 * XDIM, XDIM, 2 * XDIM, XDIM};

  // workspace layout (~264 MB); each tensor = hi plane then lo plane
  char* p = (char*)d_ws;
  auto take = [&](size_t elems) {
    short* q = (short*)p;
    p += elems * 2 * 2;  // hi + lo, 2B each
    return q;
  };
  short* x_s = take((size_t)BDIM * INDIM);
  size_t xpl = (size_t)BDIM * INDIM;
  short* w_in_s = take((size_t)XDIM * INDIM);
  size_t wpl_in = (size_t)XDIM * INDIM;
  short* w_h_s[6];
  size_t wpl_h[6];
  for (int i = 0; i < 6; i++) {
    wpl_h[i] = (size_t)XDIM * hin[i];
    w_h_s[i] = take(wpl_h[i]);
  }
  short* w_out_s = take((size_t)OUTDIM * XDIM);
  size_t wpl_out = (size_t)OUTDIM * XDIM;
  const size_t apl = (size_t)BDIM * XDIM;  // activation plane
  short* actA = take(apl);
  short* actB = take(apl);
  short* actC = take(apl);

  // 1) convert x -> hi/lo fp16
  {
    int n = BDIM * INDIM;
    cvt_split<<<dim3(n / 4 / 256), dim3(256), 0, stream>>>(
        x, (unsigned short*)x_s, (unsigned short*)(x_s + xpl), n);
  }
  // 2) transpose+split all weights: W(K,N) -> WT(N,K) hi/lo
  transpose_cvt_split<<<dim3(XDIM / 32, INDIM / 32), dim3(32, 8), 0, stream>>>(
      W_in, (unsigned short*)w_in_s, (unsigned short*)(w_in_s + wpl_in), INDIM,
      XDIM);
  for (int i = 0; i < 6; i++)
    transpose_cvt_split<<<dim3(XDIM / 32, hin[i] / 32), dim3(32, 8), 0,
                          stream>>>(Wh[i], (unsigned short*)w_h_s[i],
                                    (unsigned short*)(w_h_s[i] + wpl_h[i]),
                                    hin[i], XDIM);
  transpose_cvt_split<<<dim3(OUTDIM / 32, XDIM / 32), dim3(32, 8), 0,
                        stream>>>(W_out, (unsigned short*)w_out_s,
                                  (unsigned short*)(w_out_s + wpl_out), XDIM,
                                  OUTDIM);

  // 3) GEMM chain with 3 rotating activation buffers
  auto G = [&](const short* A1, size_t a1pl, const short* A2, size_t a2pl,
               const short* W, size_t wpl, const float* bi, const float* m,
               const int* a, short* Cb, float* Cf, int N, int K, int Ks) {
    dim3 grid(N / 128, BDIM / 128);
    const short* A2h = A2;
    const short* A2l = A2 ? A2 + a2pl : nullptr;
    if (Cb)
      gemm_split_act<true><<<grid, 256, 0, stream>>>(
          A1, A1 + a1pl, A2h, A2l, W, W + wpl, bi, m, a, (unsigned short*)Cb,
          (unsigned short*)(Cb + apl), nullptr, N, K, Ks);
    else
      gemm_split_act<false><<<grid, 256, 0, stream>>>(
          A1, A1 + a1pl, A2h, A2l, W, W + wpl, bi, m, a, nullptr, nullptr, Cf,
          N, K, Ks);
  };

  // input layer: outs[0]=actA
  G(x_s, xpl, nullptr, 0, w_in_s, wpl_in, b_in, mo_in, aid_in, actA, nullptr,
    XDIM, INDIM, INDIM);
  // L0: outs[1]=actB
  G(actA, apl, nullptr, 0, w_h_s[0], wpl_h[0], bh + 0 * XDIM, mo_h + 0 * XDIM,
    aid_h + 0 * XDIM, actB, nullptr, XDIM, XDIM, XDIM);
  // L1: outs[2]=actC
  G(actB, apl, nullptr, 0, w_h_s[1], wpl_h[1], bh + 1 * XDIM, mo_h + 1 * XDIM,
    aid_h + 1 * XDIM, actC, nullptr, XDIM, XDIM, XDIM);
  // L2 (concat outs2,outs1): outs[3]=actA
  G(actC, apl, actB, apl, w_h_s[2], wpl_h[2], bh + 2 * XDIM, mo_h + 2 * XDIM,
    aid_h + 2 * XDIM, actA, nullptr, XDIM, 2 * XDIM, XDIM);
  // L3: outs[4]=actB
  G(actA, apl, nullptr, 0, w_h_s[3], wpl_h[3], bh + 3 * XDIM, mo_h + 3 * XDIM,
    aid_h + 3 * XDIM, actB, nullptr, XDIM, XDIM, XDIM);
  // L4 (concat outs4,outs3): outs[5]=actC
  G(actB, apl, actA, apl, w_h_s[4], wpl_h[4], bh + 4 * XDIM, mo_h + 4 * XDIM,
    aid_h + 4 * XDIM, actC, nullptr, XDIM, 2 * XDIM, XDIM);
  // L5: outs[6]=actB
  G(actC, apl, nullptr, 0, w_h_s[5], wpl_h[5], bh + 5 * XDIM, mo_h + 5 * XDIM,
    aid_h + 5 * XDIM, actB, nullptr, XDIM, XDIM, XDIM);
  // output layer -> d_out (fp32)
  G(actB, apl, nullptr, 0, w_out_s, wpl_out, b_out, mo_out, aid_out, nullptr,
    (float*)d_out, OUTDIM, XDIM, XDIM);
}

// Round 4
// 1490.863 us; speedup vs baseline: 1.6234x; 1.6234x over previous
//
#include <hip/hip_runtime.h>
#include <stdint.h>
#include <string.h>

// Problem dims (fixed by the reference)
#define BDIM   4096
#define INDIM  1024
#define XDIM   2048
#define OUTDIM 512

#define LO_SCALE 2048.0f         // 2^11: lifts fp16 lo-plane out of subnormals
#define INV_LO_SCALE (1.0f / 2048.0f)

typedef _Float16 f16x8 __attribute__((ext_vector_type(8)));
typedef float f32x4 __attribute__((ext_vector_type(4)));

__device__ __forceinline__ unsigned short h2u(_Float16 h) {
  unsigned short u;
  memcpy(&u, &h, 2);
  return u;
}

// split f32 into hi fp16 + scaled-lo fp16 (combined ~22 mantissa bits)
__device__ __forceinline__ void split_h(float v, unsigned short& h,
                                        unsigned short& l) {
  _Float16 hh = (_Float16)v;                       // RTNE
  float r = v - (float)hh;                         // exact
  _Float16 ll = (_Float16)(r * LO_SCALE);          // |r|*2^11 <= |v|, no inf
  h = h2u(hh);
  l = h2u(ll);
}

// async global->LDS, 16B per lane; LDS dest wave-uniform base + lane*16
__device__ __forceinline__ void gld_lds16(const void* g, void* l) {
  __builtin_amdgcn_global_load_lds(
      (const __attribute__((address_space(1))) uint32_t*)g,
      (__attribute__((address_space(3))) uint32_t*)l, 16, 0, 0);
}

// fused RandomActivation + clip (relu/sigmoid/tanh/leaky(.1)/selu), libm-grade
__device__ __forceinline__ float rand_act(float v, int a, float mo) {
  float r;
  if (a == 0) {
    r = fmaxf(v, 0.0f);
  } else if (a == 1) {
    r = 1.0f / (1.0f + expf(-v));
  } else if (a == 2) {
    r = tanhf(v);
  } else if (a == 3) {
    r = (v >= 0.0f) ? v : 0.1f * v;
  } else {  // selu (matches jax: scale * where(v>0, v, alpha*expm1(v)))
    r = (v > 0.0f) ? 1.0507009873554805f * v
                   : 1.7580993408473766f * expm1f(v);
  }
  return fminf(r, mo);
}

// x (f32) -> hi/scaled-lo fp16 planes, 4 elems/thread
__global__ void cvt_split(const float* __restrict__ s,
                          unsigned short* __restrict__ dh,
                          unsigned short* __restrict__ dl, int n) {
  int i = (blockIdx.x * blockDim.x + threadIdx.x) * 4;
  if (i >= n) return;
  float4 v = *(const float4*)(s + i);
  ushort4 h, l;
  split_h(v.x, h.x, l.x);
  split_h(v.y, h.y, l.y);
  split_h(v.z, h.z, l.z);
  split_h(v.w, h.w, l.w);
  *(ushort4*)(dh + i) = h;
  *(ushort4*)(dl + i) = l;
}

// W (K x N, f32, row-major) -> WT hi/scaled-lo fp16 (N x K, row-major)
__global__ void transpose_cvt_split(const float* __restrict__ W,
                                    unsigned short* __restrict__ WTh,
                                    unsigned short* __restrict__ WTl, int K,
                                    int N) {
  __shared__ float t[32][33];
  int n0 = blockIdx.x * 32, k0 = blockIdx.y * 32;
  int tx = threadIdx.x, ty = threadIdx.y;  // 32 x 8
#pragma unroll
  for (int i = 0; i < 32; i += 8)
    t[ty + i][tx] = W[(size_t)(k0 + ty + i) * N + n0 + tx];
  __syncthreads();
#pragma unroll
  for (int i = 0; i < 32; i += 8) {
    float v = t[tx][ty + i];
    unsigned short h, l;
    split_h(v, h, l);
    size_t idx = (size_t)(n0 + ty + i) * K + k0 + tx;
    WTh[idx] = h;
    WTl[idx] = l;
  }
}

// C[M,N] = act( A[M,K] @ BT[N,K]^T + bias ), split-fp16 (3-term) precision.
// acc1 = hi*hi; acc2 = hi*lo' + lo'*hi at scale 2^11. Final = acc1+acc2/2^11.
// Block tile 64x128 (BM=64, BN=128), BK=32, 256 threads = 4 waves in 1x4;
// wave-tile 64x32 (4 m-frags x 2 n-frags). Grid = (N/128, BDIM/64) —
// 1024 blocks for the X-layers -> 4 blocks/CU co-resident (vs 2 at 128x128),
// which is the fix for the measured MfmaUtil=17%/Occupancy=12% latency bind.
template <bool OUT_F16>
__global__ __launch_bounds__(256, 4) void gemm_split_act(
    const short* __restrict__ A1h, const short* __restrict__ A1l,
    const short* __restrict__ A2h, const short* __restrict__ A2l,
    const short* __restrict__ BTh, const short* __restrict__ BTl,
    const float* __restrict__ bias, const float* __restrict__ mo,
    const int* __restrict__ aid, unsigned short* __restrict__ Ch,
    unsigned short* __restrict__ Cl, float* __restrict__ Cf, int N, int K,
    int Ksplit) {
  __shared__ short lAh[64 * 32];    // 4 KB
  __shared__ short lAl[64 * 32];    // 4 KB
  __shared__ short lBh[128 * 32];   // 8 KB
  __shared__ short lBl[128 * 32];   // 8 KB

  const int tid = threadIdx.x;
  const int lane = tid & 63;
  const int wave = tid >> 6;        // 0..3 = n-column of wave
  const int m16 = lane & 15, quad = lane >> 4;

  const int blockN = blockIdx.x * 128;
  const int blockM = blockIdx.y * 64;

  f32x4 acc1[4][2];  // hi*hi
  f32x4 acc2[4][2];  // (hi*lo' + lo'*hi), scale 2^11
#pragma unroll
  for (int i = 0; i < 4; i++)
#pragma unroll
    for (int j = 0; j < 2; j++) {
      acc1[i][j] = (f32x4){0.f, 0.f, 0.f, 0.f};
      acc2[i][j] = (f32x4){0.f, 0.f, 0.f, 0.f};
    }

  const int lrow = lane >> 2;       // row within 16-row chunk
  const int lcol = (lane & 3) * 8;  // f16 col offset 0/8/16/24

  for (int k0 = 0; k0 < K; k0 += 32) {
    const short *Akh, *Akl;
    int koff, lda;
    if (k0 < Ksplit) {
      Akh = A1h; Akl = A1l; koff = k0; lda = Ksplit;
    } else {
      Akh = A2h; Akl = A2l; koff = k0 - Ksplit; lda = K - Ksplit;
    }

    __syncthreads();  // previous iter's ds_reads done before overwrite
    // 24 1-KB chunks: 0-3 Ah, 4-7 Al, 8-15 Bh, 16-23 Bl; 6 per wave
    {
      int c = wave * 6;
#pragma unroll
      for (int t = 0; t < 6; t++, c++) {
        if (c < 8) {
          int cc = c & 3;
          const short* src = (c < 4 ? Akh : Akl) +
              (size_t)(blockM + cc * 16 + lrow) * lda + koff + lcol;
          short* dst = (c < 4 ? lAh : lAl) + cc * 512;
          gld_lds16(src, dst);
        } else {
          int c2 = c - 8;
          int cc = c2 & 7;
          const short* src = (c2 < 8 ? BTh : BTl) +
              (size_t)(blockN + cc * 16 + lrow) * K + k0 + lcol;
          short* dst = (c2 < 8 ? lBh : lBl) + cc * 512;
          gld_lds16(src, dst);
        }
      }
    }
    __syncthreads();  // drains vmcnt: tiles visible

    // phase 1: hi x hi -> acc1
    f16x8 aH[4], bH[2];
#pragma unroll
    for (int t = 0; t < 4; t++)
      aH[t] = *(const f16x8*)&lAh[(t * 16 + m16) * 32 + quad * 8];
#pragma unroll
    for (int t = 0; t < 2; t++)
      bH[t] = *(const f16x8*)&lBh[(wave * 32 + t * 16 + m16) * 32 + quad * 8];
#pragma unroll
    for (int i = 0; i < 4; i++)
#pragma unroll
      for (int j = 0; j < 2; j++)
        acc1[i][j] = __builtin_amdgcn_mfma_f32_16x16x32_f16(aH[i], bH[j],
                                                            acc1[i][j], 0, 0, 0);
    // phase 2: hi x lo' -> acc2
    {
      f16x8 bL[2];
#pragma unroll
      for (int t = 0; t < 2; t++)
        bL[t] = *(const f16x8*)&lBl[(wave * 32 + t * 16 + m16) * 32 + quad * 8];
#pragma unroll
      for (int i = 0; i < 4; i++)
#pragma unroll
        for (int j = 0; j < 2; j++)
          acc2[i][j] = __builtin_amdgcn_mfma_f32_16x16x32_f16(
              aH[i], bL[j], acc2[i][j], 0, 0, 0);
    }
    // phase 3: lo' x hi -> acc2
    {
      f16x8 aL[4];
#pragma unroll
      for (int t = 0; t < 4; t++)
        aL[t] = *(const f16x8*)&lAl[(t * 16 + m16) * 32 + quad * 8];
#pragma unroll
      for (int i = 0; i < 4; i++)
#pragma unroll
        for (int j = 0; j < 2; j++)
          acc2[i][j] = __builtin_amdgcn_mfma_f32_16x16x32_f16(
              aL[i], bH[j], acc2[i][j], 0, 0, 0);
    }
  }

  // epilogue: combine accs, bias + per-column activation + clip
  // C/D map col=lane&15, row=quad*4+reg (m89-verified)
#pragma unroll
  for (int j = 0; j < 2; j++) {
    int col = blockN + wave * 32 + j * 16 + m16;
    float b = bias[col];
    float m = mo[col];
    int a = aid[col];
#pragma unroll
    for (int i = 0; i < 4; i++) {
#pragma unroll
      for (int r = 0; r < 4; r++) {
        int row = blockM + i * 16 + quad * 4 + r;
        float s = acc1[i][j][r] + acc2[i][j][r] * INV_LO_SCALE;
        float v = rand_act(s + b, a, m);
        size_t idx = (size_t)row * N + col;
        if (OUT_F16) {
          unsigned short h, l;
          split_h(v, h, l);
          Ch[idx] = h;
          Cl[idx] = l;
        } else {
          Cf[idx] = v;
        }
      }
    }
  }
}

extern "C" void kernel_launch(void* const* d_in, const int* in_sizes, int n_in,
                              void* d_out, int out_size, void* d_ws,
                              size_t ws_size, hipStream_t stream) {
  (void)in_sizes; (void)n_in; (void)out_size; (void)ws_size;

  const float* x     = (const float*)d_in[0];
  const float* W_in  = (const float*)d_in[1];
  const float* b_in  = (const float*)d_in[2];
  const float* Wh[6] = {(const float*)d_in[3], (const float*)d_in[4],
                        (const float*)d_in[5], (const float*)d_in[6],
                        (const float*)d_in[7], (const float*)d_in[8]};
  const float* bh    = (const float*)d_in[9];
  const float* W_out = (const float*)d_in[10];
  const float* b_out = (const float*)d_in[11];
  const float* mo_in = (const float*)d_in[12];
  const float* mo_h  = (const float*)d_in[13];
  const float* mo_out= (const float*)d_in[14];
  const int* aid_in  = (const int*)d_in[15];
  const int* aid_h   = (const int*)d_in[16];
  const int* aid_out = (const int*)d_in[17];

  const int hin[6] = {XDIM, XDIM, 2 * XDIM, XDIM, 2 * XDIM, XDIM};

  // workspace layout (~264 MB); each tensor = hi plane then lo plane
  char* p = (char*)d_ws;
  auto take = [&](size_t elems) {
    short* q = (short*)p;
    p += elems * 2 * 2;  // hi + lo, 2B each
    return q;
  };
  short* x_s = take((size_t)BDIM * INDIM);
  size_t xpl = (size_t)BDIM * INDIM;
  short* w_in_s = take((size_t)XDIM * INDIM);
  size_t wpl_in = (size_t)XDIM * INDIM;
  short* w_h_s[6];
  size_t wpl_h[6];
  for (int i = 0; i < 6; i++) {
    wpl_h[i] = (size_t)XDIM * hin[i];
    w_h_s[i] = take(wpl_h[i]);
  }
  short* w_out_s = take((size_t)OUTDIM * XDIM);
  size_t wpl_out = (size_t)OUTDIM * XDIM;
  const size_t apl = (size_t)BDIM * XDIM;  // activation plane
  short* actA = take(apl);
  short* actB = take(apl);
  short* actC = take(apl);

  // 1) convert x -> hi/lo fp16
  {
    int n = BDIM * INDIM;
    cvt_split<<<dim3(n / 4 / 256), dim3(256), 0, stream>>>(
        x, (unsigned short*)x_s, (unsigned short*)(x_s + xpl), n);
  }
  // 2) transpose+split all weights: W(K,N) -> WT(N,K) hi/lo
  transpose_cvt_split<<<dim3(XDIM / 32, INDIM / 32), dim3(32, 8), 0, stream>>>(
      W_in, (unsigned short*)w_in_s, (unsigned short*)(w_in_s + wpl_in), INDIM,
      XDIM);
  for (int i = 0; i < 6; i++)
    transpose_cvt_split<<<dim3(XDIM / 32, hin[i] / 32), dim3(32, 8), 0,
                          stream>>>(Wh[i], (unsigned short*)w_h_s[i],
                                    (unsigned short*)(w_h_s[i] + wpl_h[i]),
                                    hin[i], XDIM);
  transpose_cvt_split<<<dim3(OUTDIM / 32, XDIM / 32), dim3(32, 8), 0,
                        stream>>>(W_out, (unsigned short*)w_out_s,
                                  (unsigned short*)(w_out_s + wpl_out), XDIM,
                                  OUTDIM);

  // 3) GEMM chain with 3 rotating activation buffers
  auto G = [&](const short* A1, size_t a1pl, const short* A2, size_t a2pl,
               const short* W, size_t wpl, const float* bi, const float* m,
               const int* a, short* Cb, float* Cf, int N, int K, int Ks) {
    dim3 grid(N / 128, BDIM / 64);
    const short* A2h = A2;
    const short* A2l = A2 ? A2 + a2pl : nullptr;
    if (Cb)
      gemm_split_act<true><<<grid, 256, 0, stream>>>(
          A1, A1 + a1pl, A2h, A2l, W, W + wpl, bi, m, a, (unsigned short*)Cb,
          (unsigned short*)(Cb + apl), nullptr, N, K, Ks);
    else
      gemm_split_act<false><<<grid, 256, 0, stream>>>(
          A1, A1 + a1pl, A2h, A2l, W, W + wpl, bi, m, a, nullptr, nullptr, Cf,
          N, K, Ks);
  };

  // input layer: outs[0]=actA
  G(x_s, xpl, nullptr, 0, w_in_s, wpl_in, b_in, mo_in, aid_in, actA, nullptr,
    XDIM, INDIM, INDIM);
  // L0: outs[1]=actB
  G(actA, apl, nullptr, 0, w_h_s[0], wpl_h[0], bh + 0 * XDIM, mo_h + 0 * XDIM,
    aid_h + 0 * XDIM, actB, nullptr, XDIM, XDIM, XDIM);
  // L1: outs[2]=actC
  G(actB, apl, nullptr, 0, w_h_s[1], wpl_h[1], bh + 1 * XDIM, mo_h + 1 * XDIM,
    aid_h + 1 * XDIM, actC, nullptr, XDIM, XDIM, XDIM);
  // L2 (concat outs2,outs1): outs[3]=actA
  G(actC, apl, actB, apl, w_h_s[2], wpl_h[2], bh + 2 * XDIM, mo_h + 2 * XDIM,
    aid_h + 2 * XDIM, actA, nullptr, XDIM, 2 * XDIM, XDIM);
  // L3: outs[4]=actB
  G(actA, apl, nullptr, 0, w_h_s[3], wpl_h[3], bh + 3 * XDIM, mo_h + 3 * XDIM,
    aid_h + 3 * XDIM, actB, nullptr, XDIM, XDIM, XDIM);
  // L4 (concat outs4,outs3): outs[5]=actC
  G(actB, apl, actA, apl, w_h_s[4], wpl_h[4], bh + 4 * XDIM, mo_h + 4 * XDIM,
    aid_h + 4 * XDIM, actC, nullptr, XDIM, 2 * XDIM, XDIM);
  // L5: outs[6]=actB
  G(actC, apl, nullptr, 0, w_h_s[5], wpl_h[5], bh + 5 * XDIM, mo_h + 5 * XDIM,
    aid_h + 5 * XDIM, actB, nullptr, XDIM, XDIM, XDIM);
  // output layer -> d_out (fp32)
  G(actB, apl, nullptr, 0, w_out_s, wpl_out, b_out, mo_out, aid_out, nullptr,
    (float*)d_out, OUTDIM, XDIM, XDIM);
}